// Round 1
// baseline (307.132 us; speedup 1.0000x reference)
//
#include <hip/hip_runtime.h>

#define B_MOL 1024
#define SEG_PER_MOL 20
#define S_SEG (B_MOL * SEG_PER_MOL)   // 20480
#define NC 16
#define H_DIM 448                      // 112 float4
#define L_DIM 28

// ---------------------------------------------------------------------------
// Kernel A: proj[b][h] = sum_l x[b][l] * W[h][l]   (Linear L->H, no bias)
// grid = B_MOL blocks, 448 threads (7 waves). W rows are 112B, float4-aligned.
// ---------------------------------------------------------------------------
__global__ __launch_bounds__(448) void proj_kernel(const float* __restrict__ x,
                                                   const float* __restrict__ W,
                                                   float* __restrict__ proj) {
    __shared__ float xs[L_DIM];
    const int b = blockIdx.x;
    const int h = threadIdx.x;
    if (h < L_DIM) xs[h] = x[b * L_DIM + h];
    __syncthreads();
    const float4* W4 = (const float4*)(W + h * L_DIM);
    float acc = 0.f;
#pragma unroll
    for (int j = 0; j < 7; ++j) {
        float4 w = W4[j];
        acc += w.x * xs[4 * j + 0] + w.y * xs[4 * j + 1] +
               w.z * xs[4 * j + 2] + w.w * xs[4 * j + 3];
    }
    proj[b * H_DIM + h] = acc;
}

// ---------------------------------------------------------------------------
// Kernel B: per-segment scores + stable log-softmax CE + accuracy.
// One block (256 thr = 4 waves) per segment. 16 lanes per candidate,
// 4 candidates per wave, 16 candidates per block.
// ---------------------------------------------------------------------------
__global__ __launch_bounds__(256) void score_ce_kernel(const float* __restrict__ proj,
                                                       const float* __restrict__ cand,
                                                       const void* __restrict__ label_pos,
                                                       float* __restrict__ out) {
    const int s    = blockIdx.x;           // segment id
    const int b    = s / SEG_PER_MOL;      // molecule id
    const int tid  = threadIdx.x;
    const int w    = tid >> 6;             // wave 0..3
    const int lane = tid & 63;
    const int g    = lane >> 4;            // candidate-group within wave
    const int li   = lane & 15;            // lane within candidate
    const int c    = w * 4 + g;            // candidate 0..15
    const size_t t = (size_t)s * NC + c;   // global candidate row

    const float4* p4 = (const float4*)(proj + (size_t)b * H_DIM);
    const float4* c4 = (const float4*)(cand + t * H_DIM);

    float acc = 0.f;
#pragma unroll
    for (int i = 0; i < 7; ++i) {
        float4 pv = p4[i * 16 + li];
        float4 cv = c4[i * 16 + li];
        acc += pv.x * cv.x + pv.y * cv.y + pv.z * cv.z + pv.w * cv.w;
    }
    // reduce across the 16 lanes of this candidate
    acc += __shfl_xor(acc, 1);
    acc += __shfl_xor(acc, 2);
    acc += __shfl_xor(acc, 4);
    acc += __shfl_xor(acc, 8);

    __shared__ float sc[NC];
    if (li == 0) sc[c] = acc;
    __syncthreads();

    if (tid == 0) {
        float m = sc[0];
#pragma unroll
        for (int i = 1; i < NC; ++i) m = fmaxf(m, sc[i]);
        float sum = 0.f;
#pragma unroll
        for (int i = 0; i < NC; ++i) sum += expf(sc[i] - m);
        float lse = logf(sum) + m;

        // label offset: robust to label_pos being int32 (JAX default) or int64
        int off = ((const int*)label_pos)[s] - s * NC;
        if (off < 0 || off >= NC) {
            long long v64 = ((const long long*)label_pos)[s];
            off = (int)(v64 - (long long)s * NC);
        }
        float ls = sc[off];

        atomicAdd(&out[0], (lse - ls) * (1.0f / B_MOL));
        if (ls >= m) atomicAdd(&out[1], 1.0f / S_SEG);
    }
}

extern "C" void kernel_launch(void* const* d_in, const int* in_sizes, int n_in,
                              void* d_out, int out_size, void* d_ws, size_t ws_size,
                              hipStream_t stream) {
    const float* x_mol = (const float*)d_in[0];   // [B, L]
    const float* A_w   = (const float*)d_in[1];   // [H, L]
    const float* cand  = (const float*)d_in[2];   // [T, H]
    // d_in[3] = batch_idx, d_in[4] = segment_ids  (analytic; unused)
    const void* label  = d_in[5];                 // [S] int32 or int64

    float* out  = (float*)d_out;                  // [loss, acc]
    float* proj = (float*)d_ws;                   // [B, H] scratch

    hipMemsetAsync(d_out, 0, (size_t)out_size * sizeof(float), stream);

    proj_kernel<<<B_MOL, 448, 0, stream>>>(x_mol, A_w, proj);
    score_ce_kernel<<<S_SEG, 256, 0, stream>>>(proj, cand, label, out);
}

// Round 2
// 114.496 us; speedup vs baseline: 2.6825x; 2.6825x over previous
//
#include <hip/hip_runtime.h>

#define B_MOL 1024
#define SEG_PER_MOL 20
#define S_SEG (B_MOL * SEG_PER_MOL)   // 20480
#define NC 16
#define H_DIM 448                      // 112 float4
#define L_DIM 28

// ---------------------------------------------------------------------------
// Kernel A: proj[b][h] = sum_l x[b][l] * W[h][l]   (Linear L->H, no bias)
// ---------------------------------------------------------------------------
__global__ __launch_bounds__(448) void proj_kernel(const float* __restrict__ x,
                                                   const float* __restrict__ W,
                                                   float* __restrict__ proj) {
    __shared__ float xs[L_DIM];
    const int b = blockIdx.x;
    const int h = threadIdx.x;
    if (h < L_DIM) xs[h] = x[b * L_DIM + h];
    __syncthreads();
    const float4* W4 = (const float4*)(W + h * L_DIM);
    float acc = 0.f;
#pragma unroll
    for (int j = 0; j < 7; ++j) {
        float4 w = W4[j];
        acc += w.x * xs[4 * j + 0] + w.y * xs[4 * j + 1] +
               w.z * xs[4 * j + 2] + w.w * xs[4 * j + 3];
    }
    proj[b * H_DIM + h] = acc;
}

// ---------------------------------------------------------------------------
// Kernel B: one WAVE per segment. 4 lanes per candidate x 16 candidates.
// All reductions via shfl; no LDS, no syncthreads, no atomics.
// Writes per-segment (loss_i, correct_i) to seg_out.
// ---------------------------------------------------------------------------
__global__ __launch_bounds__(256) void score_ce_kernel(const float* __restrict__ proj,
                                                       const float* __restrict__ cand,
                                                       const void* __restrict__ label_pos,
                                                       float2* __restrict__ seg_out) {
    const int w    = threadIdx.x >> 6;     // wave 0..3
    const int lane = threadIdx.x & 63;
    const int s    = blockIdx.x * 4 + w;   // segment id
    const int b    = s / SEG_PER_MOL;      // molecule id
    const int c    = lane >> 2;            // candidate 0..15
    const int q    = lane & 3;             // quarter-row within candidate
    const size_t t = (size_t)s * NC + c;   // global candidate row

    const float4* p4 = (const float4*)(proj + (size_t)b * H_DIM);
    const float4* c4 = (const float4*)(cand + t * H_DIM);

    float acc = 0.f;
#pragma unroll
    for (int i = 0; i < 28; ++i) {
        float4 pv = p4[i * 4 + q];
        float4 cv = c4[i * 4 + q];
        acc += pv.x * cv.x + pv.y * cv.y + pv.z * cv.z + pv.w * cv.w;
    }
    // reduce across the 4 lanes of this candidate -> all 4 hold score[c]
    acc += __shfl_xor(acc, 1);
    acc += __shfl_xor(acc, 2);

    // segment max over the 16 candidates (xor over strides 4..32 keeps one
    // representative per candidate in each q-class)
    float m = acc;
#pragma unroll
    for (int d = 4; d < 64; d <<= 1) m = fmaxf(m, __shfl_xor(m, d));

    float e = expf(acc - m);
    float sum = e;
#pragma unroll
    for (int d = 4; d < 64; d <<= 1) sum += __shfl_xor(sum, d);
    float lse = logf(sum) + m;

    // label offset: robust to label_pos being int32 (JAX default) or int64
    int off = ((const int*)label_pos)[s] - s * NC;
    if (off < 0 || off >= NC) {
        long long v64 = ((const long long*)label_pos)[s];
        off = (int)(v64 - (long long)s * NC);
    }
    float ls = __shfl(acc, off * 4);       // score of the labeled candidate

    if (lane == 0) seg_out[s] = make_float2(lse - ls, (ls >= m) ? 1.f : 0.f);
}

// ---------------------------------------------------------------------------
// Kernel C: reduce 20480 float2 -> out[0]=loss, out[1]=acc. Single block.
// ---------------------------------------------------------------------------
__global__ __launch_bounds__(1024) void reduce_kernel(const float2* __restrict__ seg,
                                                      float* __restrict__ out) {
    float a = 0.f, c = 0.f;
    for (int i = threadIdx.x; i < S_SEG; i += 1024) {
        float2 v = seg[i];
        a += v.x;
        c += v.y;
    }
#pragma unroll
    for (int d = 1; d < 64; d <<= 1) {
        a += __shfl_xor(a, d);
        c += __shfl_xor(c, d);
    }
    __shared__ float sa[16], sc[16];
    const int wv = threadIdx.x >> 6;
    if ((threadIdx.x & 63) == 0) { sa[wv] = a; sc[wv] = c; }
    __syncthreads();
    if (threadIdx.x == 0) {
        float ta = 0.f, tc = 0.f;
#pragma unroll
        for (int i = 0; i < 16; ++i) { ta += sa[i]; tc += sc[i]; }
        out[0] = ta * (1.0f / B_MOL);
        out[1] = tc * (1.0f / S_SEG);
    }
}

extern "C" void kernel_launch(void* const* d_in, const int* in_sizes, int n_in,
                              void* d_out, int out_size, void* d_ws, size_t ws_size,
                              hipStream_t stream) {
    const float* x_mol = (const float*)d_in[0];   // [B, L]
    const float* A_w   = (const float*)d_in[1];   // [H, L]
    const float* cand  = (const float*)d_in[2];   // [T, H]
    const void* label  = d_in[5];                 // [S] int32 or int64

    float* out  = (float*)d_out;                  // [loss, acc]
    float* proj = (float*)d_ws;                   // [B, H] scratch
    float2* seg = (float2*)((char*)d_ws + (size_t)B_MOL * H_DIM * sizeof(float));

    proj_kernel<<<B_MOL, 448, 0, stream>>>(x_mol, A_w, proj);
    score_ce_kernel<<<S_SEG / 4, 256, 0, stream>>>(proj, cand, label, seg);
    reduce_kernel<<<1, 1024, 0, stream>>>(seg, out);
}

// Round 3
// 93.523 us; speedup vs baseline: 3.2840x; 1.2242x over previous
//
#include <hip/hip_runtime.h>

#define B_MOL 1024
#define SEG_PER_MOL 20
#define S_SEG (B_MOL * SEG_PER_MOL)   // 20480
#define NC 16
#define H_DIM 448
#define H4 112                         // H_DIM / 4
#define L_DIM 28

typedef float v4 __attribute__((ext_vector_type(4)));

// ---------------------------------------------------------------------------
// Fused kernel: one block per molecule.
//  phase 1: proj[b] = x[b] @ W^T into LDS (448 floats)
//  phase 2: 4 waves x 5 segments each; 16 lanes per candidate, proj quarter
//           held in 7 v4 registers; cand streamed with nontemporal loads.
//  phase 3: per-block (sum loss, sum correct) -> blk_out[b]
// ---------------------------------------------------------------------------
__global__ __launch_bounds__(256) void fused_kernel(const float* __restrict__ x,
                                                    const float* __restrict__ W,
                                                    const float* __restrict__ cand,
                                                    const void* __restrict__ label_pos,
                                                    float2* __restrict__ blk_out) {
    __shared__ float xs[L_DIM];
    __shared__ float projs[H_DIM];
    const int b   = blockIdx.x;
    const int tid = threadIdx.x;

    if (tid < L_DIM) xs[tid] = x[b * L_DIM + tid];
    __syncthreads();
    for (int h = tid; h < H_DIM; h += 256) {
        const v4* W4 = (const v4*)(W + h * L_DIM);
        float acc = 0.f;
#pragma unroll
        for (int j = 0; j < 7; ++j) {
            v4 w = W4[j];
            acc += w.x * xs[4*j+0] + w.y * xs[4*j+1] +
                   w.z * xs[4*j+2] + w.w * xs[4*j+3];
        }
        projs[h] = acc;
    }
    __syncthreads();

    const int w    = tid >> 6;   // wave 0..3
    const int lane = tid & 63;
    const int g    = lane >> 4;  // candidate group 0..3 within wave
    const int li   = lane & 15;  // lane within candidate

    // proj quarter for this lane: elements [li, 16+li, ..., 96+li] (float4 units)
    v4 pv[7];
    const v4* p4 = (const v4*)projs;
#pragma unroll
    for (int i = 0; i < 7; ++i) pv[i] = p4[i * 16 + li];

    float lossw = 0.f, accw = 0.f;

    for (int sl = w; sl < SEG_PER_MOL; sl += 4) {
        const int s = b * SEG_PER_MOL + sl;
        const v4* c4 = (const v4*)(cand + (size_t)s * NC * H_DIM);

        float sc[4];   // sc[r] = score of candidate r*4+g (replicated in group)
#pragma unroll
        for (int r = 0; r < 4; ++r) {
            const v4* row = c4 + (size_t)(r * 4 + g) * H4;
            float a = 0.f;
#pragma unroll
            for (int i = 0; i < 7; ++i) {
                v4 cv = __builtin_nontemporal_load(&row[i * 16 + li]);
                a += pv[i].x * cv.x + pv[i].y * cv.y +
                     pv[i].z * cv.z + pv[i].w * cv.w;
            }
            a += __shfl_xor(a, 1);
            a += __shfl_xor(a, 2);
            a += __shfl_xor(a, 4);
            a += __shfl_xor(a, 8);
            sc[r] = a;
        }

        float m = fmaxf(fmaxf(sc[0], sc[1]), fmaxf(sc[2], sc[3]));
        m = fmaxf(m, __shfl_xor(m, 16));
        m = fmaxf(m, __shfl_xor(m, 32));
        float sum = expf(sc[0] - m) + expf(sc[1] - m) +
                    expf(sc[2] - m) + expf(sc[3] - m);
        sum += __shfl_xor(sum, 16);
        sum += __shfl_xor(sum, 32);
        float lse = logf(sum) + m;

        // label offset: robust to label_pos being int32 (JAX default) or int64
        int off = ((const int*)label_pos)[s] - s * NC;
        if (off < 0 || off >= NC) {
            long long v64 = ((const long long*)label_pos)[s];
            off = (int)(v64 - (long long)s * NC);
        }
        const int rr = off >> 2;                 // wave-uniform select
        float v = (rr == 0) ? sc[0] : (rr == 1) ? sc[1]
                : (rr == 2) ? sc[2] : sc[3];
        float ls = __shfl(v, (off & 3) * 16);    // from group off&3 (replicated)

        lossw += lse - ls;
        accw  += (ls >= m) ? 1.f : 0.f;
    }

    __shared__ float pl[4], pa[4];
    if (lane == 0) { pl[w] = lossw; pa[w] = accw; }
    __syncthreads();
    if (tid == 0)
        blk_out[b] = make_float2(pl[0] + pl[1] + pl[2] + pl[3],
                                 pa[0] + pa[1] + pa[2] + pa[3]);
}

// ---------------------------------------------------------------------------
// Final reduce: 1024 float2 -> out[0]=loss, out[1]=acc.
// ---------------------------------------------------------------------------
__global__ __launch_bounds__(256) void final_reduce(const float2* __restrict__ blk,
                                                    float* __restrict__ out) {
    float a = 0.f, c = 0.f;
    for (int i = threadIdx.x; i < B_MOL; i += 256) {
        float2 v = blk[i];
        a += v.x;
        c += v.y;
    }
#pragma unroll
    for (int d = 1; d < 64; d <<= 1) {
        a += __shfl_xor(a, d);
        c += __shfl_xor(c, d);
    }
    __shared__ float sa[4], scc[4];
    const int w = threadIdx.x >> 6;
    if ((threadIdx.x & 63) == 0) { sa[w] = a; scc[w] = c; }
    __syncthreads();
    if (threadIdx.x == 0) {
        out[0] = (sa[0] + sa[1] + sa[2] + sa[3]) * (1.0f / B_MOL);
        out[1] = (scc[0] + scc[1] + scc[2] + scc[3]) * (1.0f / S_SEG);
    }
}

extern "C" void kernel_launch(void* const* d_in, const int* in_sizes, int n_in,
                              void* d_out, int out_size, void* d_ws, size_t ws_size,
                              hipStream_t stream) {
    const float* x_mol = (const float*)d_in[0];   // [B, L]
    const float* A_w   = (const float*)d_in[1];   // [H, L]
    const float* cand  = (const float*)d_in[2];   // [T, H]
    const void* label  = d_in[5];                 // [S] int32 or int64

    float* out   = (float*)d_out;                 // [loss, acc]
    float2* blk  = (float2*)d_ws;                 // [B] partials

    fused_kernel<<<B_MOL, 256, 0, stream>>>(x_mol, A_w, cand, label, blk);
    final_reduce<<<1, 256, 0, stream>>>(blk, out);
}